// Round 8
// baseline (114.767 us; speedup 1.0000x reference)
//
#include <hip/hip_runtime.h>
#include <stdint.h>

#define BLOCK 256
#define NWAVE 4
#define CHPW  4                  // channels per wave (16 lanes each)
#define CHPG  (CHPW * NWAVE)     // 16 channels per group
#define NG    8                  // groups per block -> 128 channels/block
#define SSTR  1032               // padded floats per search channel (bank shift 8/ch)
#define KSTR  72                 // padded floats per kernel channel

__device__ __forceinline__ void gl_lds16(const float* g, float* l) {
    __builtin_amdgcn_global_load_lds(
        (__attribute__((address_space(1))) void*)(uintptr_t)g,
        (__attribute__((address_space(3))) void*)l, 16, 0, 0);
}
__device__ __forceinline__ void gl_lds4(const float* g, float* l) {
    __builtin_amdgcn_global_load_lds(
        (__attribute__((address_space(1))) void*)(uintptr_t)g,
        (__attribute__((address_space(3))) void*)l, 4, 0, 0);
}

#define WAITV(N) do { \
    asm volatile("s_waitcnt vmcnt(" #N ")" ::: "memory"); \
    __builtin_amdgcn_sched_barrier(0); \
} while (0)

// Per-wave staging of its own 4 channels: 16+4 = 20 vmem-lds ops.
__device__ __forceinline__ void stage_group(
    const float* __restrict__ srch, const float* __restrict__ kern,
    float* s_s, float* s_k, int cg, int w, int lane, int p)
{
    #pragma unroll
    for (int cl = 0; cl < CHPW; ++cl) {
        const int lch = CHPW * w + cl;
        const int ch  = cg + lch;
        const float* gs = srch + (size_t)ch * 1024;
        float* ls = s_s + p * (CHPG * SSTR) + lch * SSTR;
        #pragma unroll
        for (int t2 = 0; t2 < 4; ++t2)
            gl_lds16(gs + t2 * 256 + lane * 4, ls + t2 * 256);   // 4 x 1024B
        gl_lds4(kern + (size_t)ch * 64 + lane,
                s_k + p * (CHPG * KSTR) + lch * KSTR);           // 256B
    }
}

// Compute 4 channels (16 lanes each, lane t -> j = 2t, 2t+1). 50 stores.
__device__ __forceinline__ void compute_group(
    const float* s_s, const float* s_k, float* __restrict__ out,
    int cg, int w, int lane, int p)
{
    const int t   = lane & 15;
    const int lch = CHPW * w + (lane >> 4);
    const int tq  = (t > 12) ? 12 : t;     // clamp idle lanes' addresses
    const int j0  = 2 * tq;

    const float* sb = s_s + p * (CHPG * SSTR) + lch * SSTR + j0;
    const float* kb = s_k + p * (CHPG * KSTR) + lch * KSTR;

    float kk[64];
    #pragma unroll
    for (int q = 0; q < 16; ++q) {         // b128, 4-addr broadcast per 16-lane group
        float4 kv = ((const float4*)kb)[q];
        kk[4*q+0] = kv.x; kk[4*q+1] = kv.y; kk[4*q+2] = kv.z; kk[4*q+3] = kv.w;
    }

    float acc0[25], acc1[25];
    #pragma unroll
    for (int i = 0; i < 25; ++i) { acc0[i] = 0.0f; acc1[i] = 0.0f; }

    #pragma unroll
    for (int r = 0; r < 32; ++r) {
        float sw[10];
        #pragma unroll
        for (int s = 0; s < 5; ++s) {      // 5 aligned ds_read_b64
            float2 v = *(const float2*)&sb[r * 32 + 2 * s];
            sw[2*s] = v.x; sw[2*s+1] = v.y;
        }
        const int lo = (r > 24) ? (r - 24) : 0;
        const int hi = (r < 7) ? r : 7;
        #pragma unroll
        for (int u = 0; u < 8; ++u) {
            if (u >= lo && u <= hi) {
                const int i = r - u;
                #pragma unroll
                for (int v = 0; v < 8; ++v) {
                    const float k = kk[u * 8 + v];
                    acc0[i] = fmaf(k, sw[v],     acc0[i]);
                    acc1[i] = fmaf(k, sw[v + 1], acc1[i]);
                }
            }
        }
    }

    float* ob = out + (size_t)(cg + lch) * 625 + j0;
    if (t <= 12) {
        #pragma unroll
        for (int i = 0; i < 25; ++i) ob[i * 25] = acc0[i];
    }
    if (t <= 11) {
        #pragma unroll
        for (int i = 0; i < 25; ++i) ob[i * 25 + 1] = acc1[i];
    }
}

__global__ __launch_bounds__(BLOCK, 1) void dwxcorr_kernel(
    const float* __restrict__ kern,
    const float* __restrict__ srch,
    float* __restrict__ out)
{
    __shared__ float s_s[2 * CHPG * SSTR];   // 132,096 B
    __shared__ float s_k[2 * CHPG * KSTR];   //   9,216 B -> 1 block/CU

    const int tid  = threadIdx.x;
    const int w    = tid >> 6;
    const int lane = tid & 63;
    const int c0   = blockIdx.x * (CHPG * NG);

    // prologue
    stage_group(srch, kern, s_s, s_k, c0, w, lane, 0);

    // g = 0
    stage_group(srch, kern, s_s, s_k, c0 + CHPG, w, lane, 1);
    WAITV(20);
    compute_group(s_s, s_k, out, c0, w, lane, 0);

    // g = 1 .. NG-2: newer-than-stage(g) = 50 stores(g-1) + 20 loads(g+1) = 70 -> cap 63
    #pragma unroll 1
    for (int g = 1; g <= NG - 2; ++g) {
        stage_group(srch, kern, s_s, s_k, c0 + (g + 1) * CHPG, w, lane, (g + 1) & 1);
        WAITV(63);
        compute_group(s_s, s_k, out, c0 + g * CHPG, w, lane, g & 1);
    }

    // tail: newer-than-stage(NG-1) = 50 stores(NG-2)
    WAITV(50);
    compute_group(s_s, s_k, out, c0 + (NG - 1) * CHPG, w, lane, (NG - 1) & 1);
}

extern "C" void kernel_launch(void* const* d_in, const int* in_sizes, int n_in,
                              void* d_out, int out_size, void* d_ws, size_t ws_size,
                              hipStream_t stream) {
    const float* kern = (const float*)d_in[0];   // (128,256,8,8)
    const float* srch = (const float*)d_in[1];   // (128,256,32,32)
    float* out = (float*)d_out;                  // (128,256,25,25)

    const int nch  = in_sizes[0] / 64;           // 32768
    const int grid = nch / (CHPG * NG);          // 256
    dwxcorr_kernel<<<grid, BLOCK, 0, stream>>>(kern, srch, out);
}